// Round 3
// 342.660 us; speedup vs baseline: 1.0943x; 1.0943x over previous
//
#include <hip/hip_runtime.h>

#define H 480
#define W 640
#define NP 256
#define HW (H * W)

// Path 1: rolling-register interior. i in [16,464) = 56 bands x 8 rows; j in [32,608) = 72 groups x 8 px.
//   56*72 = 4032 threads/pair -> 16 blocks of 256 (last 64 lanes masked off).
#define P1_BLK 16
// Path 2: y-border rows (i in [0,16) U [464,480)), vectorized x path with per-sample y clamp.
//   32*72 = 2304 threads/pair = exactly 9 blocks.
#define P2_BLK 9
// Path 3: x-border columns (j in [0,32) U [608,640)), all i, scalar clamped path.
//   64*480 = 30720 threads/pair = 120 blocks.
#define P3_BLK 120

#define P1_TOTAL (NP * P1_BLK)
#define P2_TOTAL (NP * (P1_BLK + P2_BLK))
#define TOTAL_BLK (NP * (P1_BLK + P2_BLK + P3_BLK))

// ---------------- Kernel 1: 5x5 box average with replicate padding ----------
__global__ __launch_bounds__(256) void box_avg_kernel(const float* __restrict__ x,
                                                      float* __restrict__ box) {
    int idx = blockIdx.x * 256 + threadIdx.x;
    int i = idx / W;
    int j = idx - i * W;
    float s = 0.f;
#pragma unroll
    for (int dy = -2; dy <= 2; ++dy) {
        int yy = min(max(i + dy, 0), H - 1);
        const float* row = x + yy * W;
#pragma unroll
        for (int dx = -2; dx <= 2; ++dx) {
            int xx = min(max(j + dx, 0), W - 1);
            s += row[xx];
        }
    }
    box[idx] = s * 0.04f;
}

// ---- horizontal lerp of an 8-px window at static sub-offset S within 12 aligned floats ----
template<int S>
__device__ __forceinline__ void hlerp8(const float4 P, const float4 Q, const float4 R,
                                       float wx, float h[8]) {
    const float c[12] = {P.x, P.y, P.z, P.w, Q.x, Q.y, Q.z, Q.w, R.x, R.y, R.z, R.w};
#pragma unroll
    for (int k = 0; k < 8; ++k)
        h[k] = fmaf(wx, c[S + k + 1] - c[S + k], c[S + k]);
}

#define DISPATCH_H(sv, ...)                              \
    switch (sv) {                                        \
        case 0:  hlerp8<0>(__VA_ARGS__); break;          \
        case 1:  hlerp8<1>(__VA_ARGS__); break;          \
        case 2:  hlerp8<2>(__VA_ARGS__); break;          \
        default: hlerp8<3>(__VA_ARGS__); break;          \
    }

__global__ __launch_bounds__(256) void bad_desc_kernel(const float* __restrict__ box,
                                                       const float* __restrict__ po,
                                                       float* __restrict__ out) {
    int b = blockIdx.x;
    if (b < P1_TOTAL) {
        // ============ Path 1: rolling interior (no clamps possible for real inputs) ============
        int p = b >> 4;                          // P1_BLK = 16
        int t = ((b - (p << 4)) << 8) + threadIdx.x;   // 0..4095
        int band = t / 72;
        if (band >= 56) return;                  // 64 idle lanes in last block/pair
        int g = t - band * 72;
        int i0 = 16 + (band << 3);               // 16..456
        int j  = 32 + (g << 3);                  // 32..600

        float dy1 = po[p * 4 + 0];
        float dx1 = po[p * 4 + 1];
        float dy2 = po[p * 4 + 2];
        float dx2 = po[p * 4 + 3];

        float fj = (float)j;

        // x setup (px in (16, 624) for real inputs; defensive clamp for arbitrary bits)
        float xf1 = fj + dx1;
        float fl1 = floorf(xf1);
        int   x01 = (int)fl1;
        float wx1 = xf1 - fl1;
        int   s1  = __builtin_amdgcn_readfirstlane(x01 & 3);  // wave-uniform (j%8==0, dx1 uniform)
        int   m1  = min(max(x01 - (x01 & 3), 0), W - 12);     // clamp no-op for real inputs

        float xf2 = fj + dx2;
        float fl2 = floorf(xf2);
        int   x02 = (int)fl2;
        float wx2 = xf2 - fl2;
        int   s2  = __builtin_amdgcn_readfirstlane(x02 & 3);
        int   m2  = min(max(x02 - (x02 & 3), 0), W - 12);

        // y setup: frac/floor taken on dy directly; source row advances by exactly 1
        // per output row. dy in [-16,16) -> floor(dy) in [-16,15]; rA in [0,471],
        // deepest row rA+8 <= 479. Defensive clamp makes OOB impossible for any bits.
        float fdy1 = floorf(dy1);
        float wy1  = dy1 - fdy1;
        int   rA   = min(max(i0 + (int)fdy1, 0), H - 9);      // clamp no-op for real inputs
        float fdy2 = floorf(dy2);
        float wy2  = dy2 - fdy2;
        int   rB   = min(max(i0 + (int)fdy2, 0), H - 9);

        const float* baseA = box + rA * W + m1;
        const float* baseB = box + rB * W + m2;

        float h1p[8], h2p[8], h1c[8], h2c[8];
        {
            const float4* ra = (const float4*)baseA;
            const float4* rb = (const float4*)baseB;
            float4 Pa = ra[0], Qa = ra[1], Ra = ra[2];
            float4 Pb = rb[0], Qb = rb[1], Rb = rb[2];
            DISPATCH_H(s1, Pa, Qa, Ra, wx1, h1p);
            DISPATCH_H(s2, Pb, Qb, Rb, wx2, h2p);
        }

        float* o = out + ((size_t)p * HW + (size_t)i0 * W + (size_t)j);
        for (int k = 1; k <= 8; ++k) {
            const float4* ra = (const float4*)(baseA + k * W);
            const float4* rb = (const float4*)(baseB + k * W);
            float4 Pa = ra[0], Qa = ra[1], Ra = ra[2];
            float4 Pb = rb[0], Qb = rb[1], Rb = rb[2];
            DISPATCH_H(s1, Pa, Qa, Ra, wx1, h1c);
            DISPATCH_H(s2, Pb, Qb, Rb, wx2, h2c);

            float v[8];
#pragma unroll
            for (int q = 0; q < 8; ++q) {
                float a = fmaf(wy1, h1c[q] - h1p[q], h1p[q]);
                float c = fmaf(wy2, h2c[q] - h2p[q], h2p[q]);
                v[q] = a - c;
                h1p[q] = h1c[q];
                h2p[q] = h2c[q];
            }
            float4 o0 = {v[0], v[1], v[2], v[3]};
            float4 o1 = {v[4], v[5], v[6], v[7]};
            *(float4*)(o)     = o0;
            *(float4*)(o + 4) = o1;
            o += W;
        }
    } else if (b < P2_TOTAL) {
        // ============ Path 2: y-border rows, vectorized x, per-sample y clamp ============
        int b2 = b - P1_TOTAL;
        int p = b2 / P2_BLK;
        int t = (b2 - p * P2_BLK) * 256 + threadIdx.x;   // 0..2303
        int ii = t / 72;                                  // 0..31
        int g  = t - ii * 72;
        int i  = (ii < 16) ? ii : 448 + ii;               // [0,16) U [464,480)
        int j  = 32 + (g << 3);

        float dy1 = po[p * 4 + 0];
        float dx1 = po[p * 4 + 1];
        float dy2 = po[p * 4 + 2];
        float dx2 = po[p * 4 + 3];

        float fi = (float)i;
        float fj = (float)j;

        // sample 1
        float py1 = fminf(fmaxf(fi + dy1, 0.f), (float)(H - 1));
        int   ya0 = (int)py1;
        float wy1 = py1 - (float)ya0;
        int   ya1 = min(ya0 + 1, H - 1);

        float xf1 = fj + dx1;
        float fl1 = floorf(xf1);
        int   x01 = (int)fl1;
        float wx1 = xf1 - fl1;
        int   s1  = __builtin_amdgcn_readfirstlane(x01 & 3);
        int   m1  = min(max(x01 - (x01 & 3), 0), W - 12);

        const float4* r1a = (const float4*)(box + ya0 * W + m1);
        const float4* r1b = (const float4*)(box + ya1 * W + m1);
        float4 Pa = r1a[0], Qa = r1a[1], Ra = r1a[2];
        float4 Pb = r1b[0], Qb = r1b[1], Rb = r1b[2];
        float ha[8], hb[8];
        DISPATCH_H(s1, Pa, Qa, Ra, wx1, ha);
        DISPATCH_H(s1, Pb, Qb, Rb, wx1, hb);

        // sample 2
        float py2 = fminf(fmaxf(fi + dy2, 0.f), (float)(H - 1));
        int   yb0 = (int)py2;
        float wy2 = py2 - (float)yb0;
        int   yb1 = min(yb0 + 1, H - 1);

        float xf2 = fj + dx2;
        float fl2 = floorf(xf2);
        int   x02 = (int)fl2;
        float wx2 = xf2 - fl2;
        int   s2  = __builtin_amdgcn_readfirstlane(x02 & 3);
        int   m2  = min(max(x02 - (x02 & 3), 0), W - 12);

        const float4* r2a = (const float4*)(box + yb0 * W + m2);
        const float4* r2b = (const float4*)(box + yb1 * W + m2);
        float4 Pc = r2a[0], Qc = r2a[1], Rc = r2a[2];
        float4 Pd = r2b[0], Qd = r2b[1], Rd = r2b[2];
        float hc[8], hd[8];
        DISPATCH_H(s2, Pc, Qc, Rc, wx2, hc);
        DISPATCH_H(s2, Pd, Qd, Rd, wx2, hd);

        float v[8];
#pragma unroll
        for (int q = 0; q < 8; ++q) {
            float a = fmaf(wy1, hb[q] - ha[q], ha[q]);
            float c = fmaf(wy2, hd[q] - hc[q], hc[q]);
            v[q] = a - c;
        }
        float* o = out + ((size_t)p * HW + (size_t)i * W + (size_t)j);
        float4 o0 = {v[0], v[1], v[2], v[3]};
        float4 o1 = {v[4], v[5], v[6], v[7]};
        *(float4*)(o)     = o0;
        *(float4*)(o + 4) = o1;
    } else {
        // ============ Path 3: x-border, 1 px per lane, fully clamped scalar ============
        int b2 = b - P2_TOTAL;
        int p = b2 / P3_BLK;
        int t = (b2 - p * P3_BLK) * 256 + threadIdx.x;
        int i = t >> 6;          // 0..479
        int c = t & 63;
        int j = (c < 32) ? c : 576 + c;   // 0..31 or 608..639

        float dy1 = po[p * 4 + 0];
        float dx1 = po[p * 4 + 1];
        float dy2 = po[p * 4 + 2];
        float dx2 = po[p * 4 + 3];

        float fi = (float)i;
        float fj = (float)j;

        // sample 1
        float py1 = fminf(fmaxf(fi + dy1, 0.f), (float)(H - 1));
        int   ya0 = (int)py1;
        float wy1 = py1 - (float)ya0;
        int   ya1 = min(ya0 + 1, H - 1);
        const float* r1a = box + ya0 * W;
        const float* r1b = box + ya1 * W;

        float px = fminf(fmaxf(fj + dx1, 0.f), (float)(W - 1));
        int   x0 = (int)px;
        float wx = px - (float)x0;
        int   x1 = min(x0 + 1, W - 1);
        float a0 = r1a[x0], a1 = r1a[x1];
        float b0 = r1b[x0], b1 = r1b[x1];
        float h0 = fmaf(wx, a1 - a0, a0);
        float h1 = fmaf(wx, b1 - b0, b0);
        float v1 = fmaf(wy1, h1 - h0, h0);

        // sample 2
        float py2 = fminf(fmaxf(fi + dy2, 0.f), (float)(H - 1));
        int   yb0 = (int)py2;
        float wy2 = py2 - (float)yb0;
        int   yb1 = min(yb0 + 1, H - 1);
        const float* r2a = box + yb0 * W;
        const float* r2b = box + yb1 * W;

        float qx = fminf(fmaxf(fj + dx2, 0.f), (float)(W - 1));
        int   u0 = (int)qx;
        float ux = qx - (float)u0;
        int   u1 = min(u0 + 1, W - 1);
        float c0 = r2a[u0], c1 = r2a[u1];
        float d0 = r2b[u0], d1 = r2b[u1];
        float g0 = fmaf(ux, c1 - c0, c0);
        float g1 = fmaf(ux, d1 - d0, d0);
        float v2 = fmaf(wy2, g1 - g0, g0);

        out[(size_t)p * HW + (size_t)i * W + (size_t)j] = v1 - v2;
    }
}

extern "C" void kernel_launch(void* const* d_in, const int* in_sizes, int n_in,
                              void* d_out, int out_size, void* d_ws, size_t ws_size,
                              hipStream_t stream) {
    const float* x  = (const float*)d_in[0];   // [1,1,480,640]
    const float* po = (const float*)d_in[1];   // [256,2,2]
    float* out = (float*)d_out;                // [1,256,480,640]
    float* box = (float*)d_ws;                 // 480*640 floats scratch

    box_avg_kernel<<<HW / 256, 256, 0, stream>>>(x, box);
    bad_desc_kernel<<<TOTAL_BLK, 256, 0, stream>>>(box, po, out);
}

// Round 4
// 331.479 us; speedup vs baseline: 1.1312x; 1.0337x over previous
//
#include <hip/hip_runtime.h>

#define H 480
#define W 640
#define NP 256
#define HW (H * W)

// Path 1: rolling interior. i in [16,464) = 56 bands x 8 rows; j in [32,608) = 72 groups x 8 px.
//   56*72 = 4032 threads/pair -> 16 blocks of 256 (last 64 lanes masked off).
#define P1_BLK 16
// Path 2: y-border rows (i in [0,16) U [464,480)), j in [32,608): vectorized x, per-sample y clamp.
//   32*72 = 2304 threads/pair = exactly 9 blocks.
#define P2_BLK 9
// Path 3: x-border columns (j in [0,32) U [608,640)), i in [16,464): rolling column, static x clamp.
//   56 bands * 64 cols = 3584 threads/pair = exactly 14 blocks.
#define P3_BLK 14
// Path 4: corners (i border AND j border): 32*64 = 2048 px/pair = 8 blocks, 1 px/lane scalar.
#define P4_BLK 8

#define P1_TOTAL (NP * P1_BLK)
#define P2_TOTAL (NP * (P1_BLK + P2_BLK))
#define P3_TOTAL (NP * (P1_BLK + P2_BLK + P3_BLK))
#define TOTAL_BLK (NP * (P1_BLK + P2_BLK + P3_BLK + P4_BLK))

typedef float f32x4 __attribute__((ext_vector_type(4)));

__device__ __forceinline__ void nt_store4(float* p, float a, float b, float c, float d) {
    f32x4 v = {a, b, c, d};
    __builtin_nontemporal_store(v, (f32x4*)p);
}

// ---------------- Kernel 1: 5x5 box average with replicate padding ----------
__global__ __launch_bounds__(256) void box_avg_kernel(const float* __restrict__ x,
                                                      float* __restrict__ box) {
    int idx = blockIdx.x * 256 + threadIdx.x;
    int i = idx / W;
    int j = idx - i * W;
    float s = 0.f;
#pragma unroll
    for (int dy = -2; dy <= 2; ++dy) {
        int yy = min(max(i + dy, 0), H - 1);
        const float* row = x + yy * W;
#pragma unroll
        for (int dx = -2; dx <= 2; ++dx) {
            int xx = min(max(j + dx, 0), W - 1);
            s += row[xx];
        }
    }
    box[idx] = s * 0.04f;
}

// ---- horizontal lerp of an 8-px window at static sub-offset S within 12 aligned floats ----
template<int S>
__device__ __forceinline__ void hlerp8(const float4 P, const float4 Q, const float4 R,
                                       float wx, float h[8]) {
    const float c[12] = {P.x, P.y, P.z, P.w, Q.x, Q.y, Q.z, Q.w, R.x, R.y, R.z, R.w};
#pragma unroll
    for (int k = 0; k < 8; ++k)
        h[k] = fmaf(wx, c[S + k + 1] - c[S + k], c[S + k]);
}

#define DISPATCH_H(sv, ...)                              \
    switch (sv) {                                        \
        case 0:  hlerp8<0>(__VA_ARGS__); break;          \
        case 1:  hlerp8<1>(__VA_ARGS__); break;          \
        case 2:  hlerp8<2>(__VA_ARGS__); break;          \
        default: hlerp8<3>(__VA_ARGS__); break;          \
    }

__global__ __launch_bounds__(256) void bad_desc_kernel(const float* __restrict__ box,
                                                       const float* __restrict__ po,
                                                       float* __restrict__ out) {
    int b = blockIdx.x;
    if (b < P1_TOTAL) {
        // ============ Path 1: rolling interior (clamps are no-ops for real inputs) ============
        int p = b >> 4;                          // P1_BLK = 16
        int t = ((b - (p << 4)) << 8) + threadIdx.x;   // 0..4095
        int band = t / 72;
        if (band >= 56) return;                  // 64 idle lanes in last block/pair
        int g = t - band * 72;
        int i0 = 16 + (band << 3);               // 16..456
        int j  = 32 + (g << 3);                  // 32..600

        float dy1 = po[p * 4 + 0];
        float dx1 = po[p * 4 + 1];
        float dy2 = po[p * 4 + 2];
        float dx2 = po[p * 4 + 3];

        float fj = (float)j;

        // x setup (px in (16,624) for real inputs; defensive clamp for arbitrary bits)
        float xf1 = fj + dx1;
        float fl1 = floorf(xf1);
        int   x01 = (int)fl1;
        float wx1 = xf1 - fl1;
        int   s1  = __builtin_amdgcn_readfirstlane(x01 & 3);  // wave-uniform (j%4==0, dx1 uniform)
        int   m1  = min(max(x01 - (x01 & 3), 0), W - 12);

        float xf2 = fj + dx2;
        float fl2 = floorf(xf2);
        int   x02 = (int)fl2;
        float wx2 = xf2 - fl2;
        int   s2  = __builtin_amdgcn_readfirstlane(x02 & 3);
        int   m2  = min(max(x02 - (x02 & 3), 0), W - 12);

        // y: source row advances by exactly 1 per output row. dy in [-16,16) ->
        // rA in [0,471], deepest row rA+8 <= 479. Defensive clamp for any bits.
        float fdy1 = floorf(dy1);
        float wy1  = dy1 - fdy1;
        int   rA   = min(max(i0 + (int)fdy1, 0), H - 9);
        float fdy2 = floorf(dy2);
        float wy2  = dy2 - fdy2;
        int   rB   = min(max(i0 + (int)fdy2, 0), H - 9);

        const float* baseA = box + rA * W + m1;
        const float* baseB = box + rB * W + m2;

        float h1p[8], h2p[8], h1c[8], h2c[8];
        {
            const float4* ra = (const float4*)baseA;
            const float4* rb = (const float4*)baseB;
            float4 Pa = ra[0], Qa = ra[1], Ra = ra[2];
            float4 Pb = rb[0], Qb = rb[1], Rb = rb[2];
            DISPATCH_H(s1, Pa, Qa, Ra, wx1, h1p);
            DISPATCH_H(s2, Pb, Qb, Rb, wx2, h2p);
        }

        float* o = out + ((size_t)p * HW + (size_t)i0 * W + (size_t)j);
        for (int k = 1; k <= 8; ++k) {
            const float4* ra = (const float4*)(baseA + k * W);
            const float4* rb = (const float4*)(baseB + k * W);
            float4 Pa = ra[0], Qa = ra[1], Ra = ra[2];
            float4 Pb = rb[0], Qb = rb[1], Rb = rb[2];
            DISPATCH_H(s1, Pa, Qa, Ra, wx1, h1c);
            DISPATCH_H(s2, Pb, Qb, Rb, wx2, h2c);

            float v[8];
#pragma unroll
            for (int q = 0; q < 8; ++q) {
                float a = fmaf(wy1, h1c[q] - h1p[q], h1p[q]);
                float c = fmaf(wy2, h2c[q] - h2p[q], h2p[q]);
                v[q] = a - c;
                h1p[q] = h1c[q];
                h2p[q] = h2c[q];
            }
            nt_store4(o,     v[0], v[1], v[2], v[3]);
            nt_store4(o + 4, v[4], v[5], v[6], v[7]);
            o += W;
        }
    } else if (b < P2_TOTAL) {
        // ============ Path 2: y-border rows, vectorized x, per-sample y clamp ============
        int b2 = b - P1_TOTAL;
        int p = b2 / P2_BLK;
        int t = (b2 - p * P2_BLK) * 256 + threadIdx.x;   // 0..2303
        int ii = t / 72;                                  // 0..31
        int g  = t - ii * 72;
        int i  = (ii < 16) ? ii : 448 + ii;               // [0,16) U [464,480)
        int j  = 32 + (g << 3);

        float dy1 = po[p * 4 + 0];
        float dx1 = po[p * 4 + 1];
        float dy2 = po[p * 4 + 2];
        float dx2 = po[p * 4 + 3];

        float fi = (float)i;
        float fj = (float)j;

        // sample 1
        float py1 = fminf(fmaxf(fi + dy1, 0.f), (float)(H - 1));
        int   ya0 = (int)py1;
        float wy1 = py1 - (float)ya0;
        int   ya1 = min(ya0 + 1, H - 1);

        float xf1 = fj + dx1;
        float fl1 = floorf(xf1);
        int   x01 = (int)fl1;
        float wx1 = xf1 - fl1;
        int   s1  = __builtin_amdgcn_readfirstlane(x01 & 3);
        int   m1  = min(max(x01 - (x01 & 3), 0), W - 12);

        const float4* r1a = (const float4*)(box + ya0 * W + m1);
        const float4* r1b = (const float4*)(box + ya1 * W + m1);
        float4 Pa = r1a[0], Qa = r1a[1], Ra = r1a[2];
        float4 Pb = r1b[0], Qb = r1b[1], Rb = r1b[2];
        float ha[8], hb[8];
        DISPATCH_H(s1, Pa, Qa, Ra, wx1, ha);
        DISPATCH_H(s1, Pb, Qb, Rb, wx1, hb);

        // sample 2
        float py2 = fminf(fmaxf(fi + dy2, 0.f), (float)(H - 1));
        int   yb0 = (int)py2;
        float wy2 = py2 - (float)yb0;
        int   yb1 = min(yb0 + 1, H - 1);

        float xf2 = fj + dx2;
        float fl2 = floorf(xf2);
        int   x02 = (int)fl2;
        float wx2 = xf2 - fl2;
        int   s2  = __builtin_amdgcn_readfirstlane(x02 & 3);
        int   m2  = min(max(x02 - (x02 & 3), 0), W - 12);

        const float4* r2a = (const float4*)(box + yb0 * W + m2);
        const float4* r2b = (const float4*)(box + yb1 * W + m2);
        float4 Pc = r2a[0], Qc = r2a[1], Rc = r2a[2];
        float4 Pd = r2b[0], Qd = r2b[1], Rd = r2b[2];
        float hc[8], hd[8];
        DISPATCH_H(s2, Pc, Qc, Rc, wx2, hc);
        DISPATCH_H(s2, Pd, Qd, Rd, wx2, hd);

        float v[8];
#pragma unroll
        for (int q = 0; q < 8; ++q) {
            float a = fmaf(wy1, hb[q] - ha[q], ha[q]);
            float c = fmaf(wy2, hd[q] - hc[q], hc[q]);
            v[q] = a - c;
        }
        float* o = out + ((size_t)p * HW + (size_t)i * W + (size_t)j);
        nt_store4(o,     v[0], v[1], v[2], v[3]);
        nt_store4(o + 4, v[4], v[5], v[6], v[7]);
    } else if (b < P3_TOTAL) {
        // ============ Path 3: x-border rolling column (static x clamp, y rolls) ============
        int b2 = b - P2_TOTAL;
        int p = b2 / P3_BLK;
        int t = (b2 - p * P3_BLK) * 256 + threadIdx.x;   // 0..3583
        int band = t >> 6;                                // 0..55 (wave-uniform)
        int c = t & 63;
        int i0 = 16 + (band << 3);                        // 16..456
        int j  = (c < 32) ? c : 576 + c;                  // [0,32) U [608,640)

        float dy1 = po[p * 4 + 0];
        float dx1 = po[p * 4 + 1];
        float dy2 = po[p * 4 + 2];
        float dx2 = po[p * 4 + 3];

        float fj = (float)j;

        // x: clamped, static across all 8 rows of the column
        float px1 = fminf(fmaxf(fj + dx1, 0.f), (float)(W - 1));
        int   xa0 = (int)px1;
        float wxa = px1 - (float)xa0;
        int   xa1 = min(xa0 + 1, W - 1);

        float px2 = fminf(fmaxf(fj + dx2, 0.f), (float)(W - 1));
        int   xb0 = (int)px2;
        float wxb = px2 - (float)xb0;
        int   xb1 = min(xb0 + 1, W - 1);

        // y: same rolling recurrence as Path 1 (i in [16,464) -> no y clamp possible)
        float fdy1 = floorf(dy1);
        float wy1  = dy1 - fdy1;
        int   rA   = min(max(i0 + (int)fdy1, 0), H - 9);
        float fdy2 = floorf(dy2);
        float wy2  = dy2 - fdy2;
        int   rB   = min(max(i0 + (int)fdy2, 0), H - 9);

        const float* pA = box + rA * W;
        const float* pB = box + rB * W;

        float a0 = pA[xa0], a1 = pA[xa1];
        float h1p = fmaf(wxa, a1 - a0, a0);
        float b0 = pB[xb0], b1 = pB[xb1];
        float h2p = fmaf(wxb, b1 - b0, b0);

        float* o = out + ((size_t)p * HW + (size_t)i0 * W + (size_t)j);
        for (int k = 1; k <= 8; ++k) {
            const float* qA = pA + k * W;
            const float* qB = pB + k * W;
            float c0 = qA[xa0], c1 = qA[xa1];
            float h1c = fmaf(wxa, c1 - c0, c0);
            float d0 = qB[xb0], d1 = qB[xb1];
            float h2c = fmaf(wxb, d1 - d0, d0);

            float va = fmaf(wy1, h1c - h1p, h1p);
            float vb = fmaf(wy2, h2c - h2p, h2p);
            __builtin_nontemporal_store(va - vb, o);
            h1p = h1c;
            h2p = h2c;
            o += W;
        }
    } else {
        // ============ Path 4: corners, 1 px per lane, fully clamped scalar ============
        int b2 = b - P3_TOTAL;
        int p = b2 >> 3;                                  // P4_BLK = 8
        int t = ((b2 - (p << 3)) << 8) + threadIdx.x;     // 0..2047
        int ii = t >> 6;                                  // 0..31
        int c = t & 63;
        int i = (ii < 16) ? ii : 448 + ii;                // [0,16) U [464,480)
        int j = (c < 32) ? c : 576 + c;                   // [0,32) U [608,640)

        float dy1 = po[p * 4 + 0];
        float dx1 = po[p * 4 + 1];
        float dy2 = po[p * 4 + 2];
        float dx2 = po[p * 4 + 3];

        float fi = (float)i;
        float fj = (float)j;

        // sample 1
        float py1 = fminf(fmaxf(fi + dy1, 0.f), (float)(H - 1));
        int   ya0 = (int)py1;
        float wy1 = py1 - (float)ya0;
        int   ya1 = min(ya0 + 1, H - 1);
        const float* r1a = box + ya0 * W;
        const float* r1b = box + ya1 * W;

        float px = fminf(fmaxf(fj + dx1, 0.f), (float)(W - 1));
        int   x0 = (int)px;
        float wx = px - (float)x0;
        int   x1 = min(x0 + 1, W - 1);
        float a0 = r1a[x0], a1 = r1a[x1];
        float b0 = r1b[x0], b1 = r1b[x1];
        float h0 = fmaf(wx, a1 - a0, a0);
        float h1 = fmaf(wx, b1 - b0, b0);
        float v1 = fmaf(wy1, h1 - h0, h0);

        // sample 2
        float py2 = fminf(fmaxf(fi + dy2, 0.f), (float)(H - 1));
        int   yb0 = (int)py2;
        float wy2 = py2 - (float)yb0;
        int   yb1 = min(yb0 + 1, H - 1);
        const float* r2a = box + yb0 * W;
        const float* r2b = box + yb1 * W;

        float qx = fminf(fmaxf(fj + dx2, 0.f), (float)(W - 1));
        int   u0 = (int)qx;
        float ux = qx - (float)u0;
        int   u1 = min(u0 + 1, W - 1);
        float c0 = r2a[u0], c1 = r2a[u1];
        float d0 = r2b[u0], d1 = r2b[u1];
        float g0 = fmaf(ux, c1 - c0, c0);
        float g1 = fmaf(ux, d1 - d0, d0);
        float v2 = fmaf(wy2, g1 - g0, g0);

        __builtin_nontemporal_store(v1 - v2, out + ((size_t)p * HW + (size_t)i * W + (size_t)j));
    }
}

extern "C" void kernel_launch(void* const* d_in, const int* in_sizes, int n_in,
                              void* d_out, int out_size, void* d_ws, size_t ws_size,
                              hipStream_t stream) {
    const float* x  = (const float*)d_in[0];   // [1,1,480,640]
    const float* po = (const float*)d_in[1];   // [256,2,2]
    float* out = (float*)d_out;                // [1,256,480,640]
    float* box = (float*)d_ws;                 // 480*640 floats scratch

    box_avg_kernel<<<HW / 256, 256, 0, stream>>>(x, box);
    bad_desc_kernel<<<TOTAL_BLK, 256, 0, stream>>>(box, po, out);
}

// Round 7
// 320.814 us; speedup vs baseline: 1.1688x; 1.0332x over previous
//
#include <hip/hip_runtime.h>

#define H 480
#define W 640
#define NP 256
#define HW (H * W)

// Path 1: dense-store rolling interior. i in [16,464) = 56 bands x 8 rows;
//   j in [64,576) = 64 groups x 8 px. One wave == one (band,row-slice): 56*64 = 3584
//   threads/pair = 14 blocks. Each wave's output row segment is a contiguous 2 KB.
#define P1_BLK 14
// Path 2: y-border rows (i in [0,16) U [464,480)), j in [64,576): vectorized x, y clamp.
//   32 rows * 64 groups = 2048 threads/pair = 8 blocks.
#define P2_BLK 8
// Path 3: x-border columns (j in [0,64) U [576,640) = 128 cols), i in [16,464): rolling column.
//   56 bands * 128 cols = 7168 threads/pair = 28 blocks.
#define P3_BLK 28
// Path 4: corners (i border AND j border): 32*128 = 4096 px/pair = 16 blocks, 1 px/lane.
#define P4_BLK 16

#define P1_TOTAL (NP * P1_BLK)
#define P2_TOTAL (NP * (P1_BLK + P2_BLK))
#define P3_TOTAL (NP * (P1_BLK + P2_BLK + P3_BLK))
#define TOTAL_BLK (NP * (P1_BLK + P2_BLK + P3_BLK + P4_BLK))

typedef float f32x4 __attribute__((ext_vector_type(4)));

__device__ __forceinline__ void nt_store4(float* p, float a, float b, float c, float d) {
    f32x4 v = {a, b, c, d};
    __builtin_nontemporal_store(v, (f32x4*)p);
}

// ---------------- Kernel 1: 5x5 box average with replicate padding ----------
__global__ __launch_bounds__(256) void box_avg_kernel(const float* __restrict__ x,
                                                      float* __restrict__ box) {
    int idx = blockIdx.x * 256 + threadIdx.x;
    int i = idx / W;
    int j = idx - i * W;
    float s = 0.f;
#pragma unroll
    for (int dy = -2; dy <= 2; ++dy) {
        int yy = min(max(i + dy, 0), H - 1);
        const float* row = x + yy * W;
#pragma unroll
        for (int dx = -2; dx <= 2; ++dx) {
            int xx = min(max(j + dx, 0), W - 1);
            s += row[xx];
        }
    }
    box[idx] = s * 0.04f;
}

// ---- horizontal lerp of an 8-px window at static sub-offset S within 12 aligned floats ----
template<int S>
__device__ __forceinline__ void hlerp8(const float4 P, const float4 Q, const float4 R,
                                       float wx, float h[8]) {
    const float c[12] = {P.x, P.y, P.z, P.w, Q.x, Q.y, Q.z, Q.w, R.x, R.y, R.z, R.w};
#pragma unroll
    for (int k = 0; k < 8; ++k)
        h[k] = fmaf(wx, c[S + k + 1] - c[S + k], c[S + k]);
}

#define DISPATCH_H(sv, ...)                              \
    switch (sv) {                                        \
        case 0:  hlerp8<0>(__VA_ARGS__); break;          \
        case 1:  hlerp8<1>(__VA_ARGS__); break;          \
        case 2:  hlerp8<2>(__VA_ARGS__); break;          \
        default: hlerp8<3>(__VA_ARGS__); break;          \
    }

__global__ __launch_bounds__(256) void bad_desc_kernel(const float* __restrict__ box,
                                                       const float* __restrict__ po,
                                                       float* __restrict__ out) {
    int b = blockIdx.x;
    if (b < P1_TOTAL) {
        // ============ Path 1: rolling interior with wave-dense packed stores ============
        int p = b / P1_BLK;
        int t = (b - p * P1_BLK) * 256 + threadIdx.x;   // 0..3583
        int band = t >> 6;                               // 0..55, wave-uniform
        int g = t & 63;                                  // lane == group
        int i0 = 16 + (band << 3);                       // 16..456
        int j  = 64 + (g << 3);                          // 64..568

        float dy1 = po[p * 4 + 0];
        float dx1 = po[p * 4 + 1];
        float dy2 = po[p * 4 + 2];
        float dx2 = po[p * 4 + 3];

        float fj = (float)j;

        // x setup (px in (48,592) for real inputs; defensive clamp for arbitrary bits)
        float xf1 = fj + dx1;
        float fl1 = floorf(xf1);
        int   x01 = (int)fl1;
        float wx1 = xf1 - fl1;
        int   s1  = __builtin_amdgcn_readfirstlane(x01 & 3);  // wave-uniform (j%4==0, dx1 uniform)
        int   m1  = min(max(x01 - (x01 & 3), 0), W - 12);

        float xf2 = fj + dx2;
        float fl2 = floorf(xf2);
        int   x02 = (int)fl2;
        float wx2 = xf2 - fl2;
        int   s2  = __builtin_amdgcn_readfirstlane(x02 & 3);
        int   m2  = min(max(x02 - (x02 & 3), 0), W - 12);

        // y: source row advances by exactly 1 per output row. dy in [-16,16) ->
        // rA in [0,471], deepest row rA+8 <= 479. Defensive clamp for any bits.
        float fdy1 = floorf(dy1);
        float wy1  = dy1 - fdy1;
        int   rA   = min(max(i0 + (int)fdy1, 0), H - 9);
        float fdy2 = floorf(dy2);
        float wy2  = dy2 - fdy2;
        int   rB   = min(max(i0 + (int)fdy2, 0), H - 9);

        const float* baseA = box + rA * W + m1;
        const float* baseB = box + rB * W + m2;

        float h1p[8], h2p[8], h1c[8], h2c[8];
        {
            const float4* ra = (const float4*)baseA;
            const float4* rb = (const float4*)baseB;
            float4 Pa = ra[0], Qa = ra[1], Ra = ra[2];
            float4 Pb = rb[0], Qb = rb[1], Rb = rb[2];
            DISPATCH_H(s1, Pa, Qa, Ra, wx1, h1p);
            DISPATCH_H(s2, Pb, Qb, Rb, wx2, h2p);
        }

        int lane = g;                     // == threadIdx.x & 63
        int sA = lane >> 1;               // src lane for low-half chunks
        int sB = sA + 32;                 // src lane for high-half chunks
        int odd = lane & 1;
        // wave-uniform output row base (px j=64 of row i0 of pair p)
        float* rowo = out + ((size_t)p * HW + (size_t)i0 * W + 64);

        for (int k = 1; k <= 8; ++k) {
            const float4* ra = (const float4*)(baseA + k * W);
            const float4* rb = (const float4*)(baseB + k * W);
            float4 Pa = ra[0], Qa = ra[1], Ra = ra[2];
            float4 Pb = rb[0], Qb = rb[1], Rb = rb[2];
            DISPATCH_H(s1, Pa, Qa, Ra, wx1, h1c);
            DISPATCH_H(s2, Pb, Qb, Rb, wx2, h2c);

            float v[8];
#pragma unroll
            for (int q = 0; q < 8; ++q) {
                float a = fmaf(wy1, h1c[q] - h1p[q], h1p[q]);
                float c = fmaf(wy2, h2c[q] - h2p[q], h2p[q]);
                v[q] = a - c;
                h1p[q] = h1c[q];
                h2p[q] = h2c[q];
            }
            // ---- pack: lane l takes 16B chunk l of the wave's contiguous 2KB row span.
            // chunk 2m = v[0..3] of lane m; chunk 2m+1 = v[4..7] of lane m.
            float A[4], Bv[4];
#pragma unroll
            for (int d = 0; d < 4; ++d) {
                float p0 = __shfl(v[d],     sA, 64);
                float p1 = __shfl(v[d + 4], sA, 64);
                A[d] = odd ? p1 : p0;
                float q0 = __shfl(v[d],     sB, 64);
                float q1 = __shfl(v[d + 4], sB, 64);
                Bv[d] = odd ? q1 : q0;
            }
            // iteration k computes output row i0+(k-1)  (rows rA+k-1, rA+k of box)
            float* ro = rowo + (size_t)(k - 1) * W;
            nt_store4(ro + (lane << 2),        A[0],  A[1],  A[2],  A[3]);   // bytes [0,1024)
            nt_store4(ro + 256 + (lane << 2),  Bv[0], Bv[1], Bv[2], Bv[3]);  // bytes [1024,2048)
        }
    } else if (b < P2_TOTAL) {
        // ============ Path 2: y-border rows, vectorized x, per-sample y clamp ============
        int b2 = b - P1_TOTAL;
        int p = b2 / P2_BLK;
        int t = (b2 - p * P2_BLK) * 256 + threadIdx.x;   // 0..2047
        int ii = t >> 6;                                  // 0..31
        int g  = t & 63;
        int i  = (ii < 16) ? ii : 448 + ii;               // [0,16) U [464,480)
        int j  = 64 + (g << 3);

        float dy1 = po[p * 4 + 0];
        float dx1 = po[p * 4 + 1];
        float dy2 = po[p * 4 + 2];
        float dx2 = po[p * 4 + 3];

        float fi = (float)i;
        float fj = (float)j;

        // sample 1
        float py1 = fminf(fmaxf(fi + dy1, 0.f), (float)(H - 1));
        int   ya0 = (int)py1;
        float wy1 = py1 - (float)ya0;
        int   ya1 = min(ya0 + 1, H - 1);

        float xf1 = fj + dx1;
        float fl1 = floorf(xf1);
        int   x01 = (int)fl1;
        float wx1 = xf1 - fl1;
        int   s1  = __builtin_amdgcn_readfirstlane(x01 & 3);
        int   m1  = min(max(x01 - (x01 & 3), 0), W - 12);

        const float4* r1a = (const float4*)(box + ya0 * W + m1);
        const float4* r1b = (const float4*)(box + ya1 * W + m1);
        float4 Pa = r1a[0], Qa = r1a[1], Ra = r1a[2];
        float4 Pb = r1b[0], Qb = r1b[1], Rb = r1b[2];
        float ha[8], hb[8];
        DISPATCH_H(s1, Pa, Qa, Ra, wx1, ha);
        DISPATCH_H(s1, Pb, Qb, Rb, wx1, hb);

        // sample 2
        float py2 = fminf(fmaxf(fi + dy2, 0.f), (float)(H - 1));
        int   yb0 = (int)py2;
        float wy2 = py2 - (float)yb0;
        int   yb1 = min(yb0 + 1, H - 1);

        float xf2 = fj + dx2;
        float fl2 = floorf(xf2);
        int   x02 = (int)fl2;
        float wx2 = xf2 - fl2;
        int   s2  = __builtin_amdgcn_readfirstlane(x02 & 3);
        int   m2  = min(max(x02 - (x02 & 3), 0), W - 12);

        const float4* r2a = (const float4*)(box + yb0 * W + m2);
        const float4* r2b = (const float4*)(box + yb1 * W + m2);
        float4 Pc = r2a[0], Qc = r2a[1], Rc = r2a[2];
        float4 Pd = r2b[0], Qd = r2b[1], Rd = r2b[2];
        float hc[8], hd[8];
        DISPATCH_H(s2, Pc, Qc, Rc, wx2, hc);
        DISPATCH_H(s2, Pd, Qd, Rd, wx2, hd);

        float v[8];
#pragma unroll
        for (int q = 0; q < 8; ++q) {
            float a = fmaf(wy1, hb[q] - ha[q], ha[q]);
            float c = fmaf(wy2, hd[q] - hc[q], hc[q]);
            v[q] = a - c;
        }
        float* o = out + ((size_t)p * HW + (size_t)i * W + (size_t)j);
        nt_store4(o,     v[0], v[1], v[2], v[3]);
        nt_store4(o + 4, v[4], v[5], v[6], v[7]);
    } else if (b < P3_TOTAL) {
        // ============ Path 3: x-border rolling column (static x clamp, y rolls) ============
        int b2 = b - P2_TOTAL;
        int p = b2 / P3_BLK;
        int t = (b2 - p * P3_BLK) * 256 + threadIdx.x;   // 0..7167
        int band = t >> 7;                                // 0..55
        int c = t & 127;
        int i0 = 16 + (band << 3);                        // 16..456
        int j  = (c < 64) ? c : 512 + c;                  // [0,64) U [576,640)

        float dy1 = po[p * 4 + 0];
        float dx1 = po[p * 4 + 1];
        float dy2 = po[p * 4 + 2];
        float dx2 = po[p * 4 + 3];

        float fj = (float)j;

        // x: clamped, static across all 8 rows of the column
        float px1 = fminf(fmaxf(fj + dx1, 0.f), (float)(W - 1));
        int   xa0 = (int)px1;
        float wxa = px1 - (float)xa0;
        int   xa1 = min(xa0 + 1, W - 1);

        float px2 = fminf(fmaxf(fj + dx2, 0.f), (float)(W - 1));
        int   xb0 = (int)px2;
        float wxb = px2 - (float)xb0;
        int   xb1 = min(xb0 + 1, W - 1);

        // y: same rolling recurrence as Path 1 (i in [16,464) -> no y clamp possible)
        float fdy1 = floorf(dy1);
        float wy1  = dy1 - fdy1;
        int   rA   = min(max(i0 + (int)fdy1, 0), H - 9);
        float fdy2 = floorf(dy2);
        float wy2  = dy2 - fdy2;
        int   rB   = min(max(i0 + (int)fdy2, 0), H - 9);

        const float* pA = box + rA * W;
        const float* pB = box + rB * W;

        float a0 = pA[xa0], a1 = pA[xa1];
        float h1p = fmaf(wxa, a1 - a0, a0);
        float b0 = pB[xb0], b1 = pB[xb1];
        float h2p = fmaf(wxb, b1 - b0, b0);

        float* o = out + ((size_t)p * HW + (size_t)i0 * W + (size_t)j);
        for (int k = 1; k <= 8; ++k) {
            const float* qA = pA + k * W;
            const float* qB = pB + k * W;
            float c0 = qA[xa0], c1 = qA[xa1];
            float h1c = fmaf(wxa, c1 - c0, c0);
            float d0 = qB[xb0], d1 = qB[xb1];
            float h2c = fmaf(wxb, d1 - d0, d0);

            float va = fmaf(wy1, h1c - h1p, h1p);
            float vb = fmaf(wy2, h2c - h2p, h2p);
            __builtin_nontemporal_store(va - vb, o);
            h1p = h1c;
            h2p = h2c;
            o += W;
        }
    } else {
        // ============ Path 4: corners, 1 px per lane, fully clamped scalar ============
        int b2 = b - P3_TOTAL;
        int p = b2 / P4_BLK;
        int t = (b2 - p * P4_BLK) * 256 + threadIdx.x;    // 0..4095
        int ii = t >> 7;                                  // 0..31
        int c = t & 127;
        int i = (ii < 16) ? ii : 448 + ii;                // [0,16) U [464,480)
        int j = (c < 64) ? c : 512 + c;                   // [0,64) U [576,640)

        float dy1 = po[p * 4 + 0];
        float dx1 = po[p * 4 + 1];
        float dy2 = po[p * 4 + 2];
        float dx2 = po[p * 4 + 3];

        float fi = (float)i;
        float fj = (float)j;

        // sample 1
        float py1 = fminf(fmaxf(fi + dy1, 0.f), (float)(H - 1));
        int   ya0 = (int)py1;
        float wy1 = py1 - (float)ya0;
        int   ya1 = min(ya0 + 1, H - 1);
        const float* r1a = box + ya0 * W;
        const float* r1b = box + ya1 * W;

        float px = fminf(fmaxf(fj + dx1, 0.f), (float)(W - 1));
        int   x0 = (int)px;
        float wx = px - (float)x0;
        int   x1 = min(x0 + 1, W - 1);
        float a0 = r1a[x0], a1 = r1a[x1];
        float b0 = r1b[x0], b1 = r1b[x1];
        float h0 = fmaf(wx, a1 - a0, a0);
        float h1 = fmaf(wx, b1 - b0, b0);
        float v1 = fmaf(wy1, h1 - h0, h0);

        // sample 2
        float py2 = fminf(fmaxf(fi + dy2, 0.f), (float)(H - 1));
        int   yb0 = (int)py2;
        float wy2 = py2 - (float)yb0;
        int   yb1 = min(yb0 + 1, H - 1);
        const float* r2a = box + yb0 * W;
        const float* r2b = box + yb1 * W;

        float qx = fminf(fmaxf(fj + dx2, 0.f), (float)(W - 1));
        int   u0 = (int)qx;
        float ux = qx - (float)u0;
        int   u1 = min(u0 + 1, W - 1);
        float c0 = r2a[u0], c1 = r2a[u1];
        float d0 = r2b[u0], d1 = r2b[u1];
        float g0 = fmaf(ux, c1 - c0, c0);
        float g1 = fmaf(ux, d1 - d0, d0);
        float v2 = fmaf(wy2, g1 - g0, g0);

        __builtin_nontemporal_store(v1 - v2, out + ((size_t)p * HW + (size_t)i * W + (size_t)j));
    }
}

extern "C" void kernel_launch(void* const* d_in, const int* in_sizes, int n_in,
                              void* d_out, int out_size, void* d_ws, size_t ws_size,
                              hipStream_t stream) {
    const float* x  = (const float*)d_in[0];   // [1,1,480,640]
    const float* po = (const float*)d_in[1];   // [256,2,2]
    float* out = (float*)d_out;                // [1,256,480,640]
    float* box = (float*)d_ws;                 // 480*640 floats scratch

    box_avg_kernel<<<HW / 256, 256, 0, stream>>>(x, box);
    bad_desc_kernel<<<TOTAL_BLK, 256, 0, stream>>>(box, po, out);
}